// Round 9
// baseline (380.676 us; speedup 1.0000x reference)
//
#include <hip/hip_runtime.h>
#include <hip/hip_bf16.h>

// TMDConv (PaiNN/TorchMD-style) two-pass message passing on MI355X.
// R9 = R8 + correctness fix:
//  - R8 BUG: phase A executed __shfl(jv, e) with only tid<16 active; CDNA
//    ds_bpermute returns undefined/0 when the SOURCE lane is exec-inactive.
//    R7 (tid<32) only needed inactive sources for deg>32 (never happens);
//    R8's 16-batch hit it for deg>16 (~2.7% of nodes) -> absmax 5.0.
//  - FIX: all 64 lanes of wave 0 execute the shfl (e = bs + (lane&15), always
//    <=63), body predicated AFTER the shfl. Phase-B / pass2 shfls sit in
//    wave-uniform branches (all lanes active) -> safe as-is.

#define F_DIM   128
#define F3_DIM  384
#define L_DIM   20
#define CAP     64          // max in-degree bucket capacity
#define BATCH   16

typedef __attribute__((ext_vector_type(8))) short short8;
typedef __attribute__((ext_vector_type(4))) float f32x4;
typedef __attribute__((ext_vector_type(4))) unsigned short us4;

struct u3 { unsigned a, b, c; };   // 12B record (dwordx3)

__device__ __forceinline__ unsigned short f2bf(float f) {
  union { float f; unsigned u; } a; a.f = f;
  unsigned u = a.u;
  u = (u + 0x7FFFu + ((u >> 16) & 1u)) >> 16;   // RNE
  return (unsigned short)u;
}
__device__ __forceinline__ float bf2f(unsigned short u) {
  union { unsigned u; float f; } a; a.u = ((unsigned)u) << 16;
  return a.f;
}

// ---------------------------------------------------------------------------
// fused cast+fill kernel
__global__ __launch_bounds__(256) void cast_fill_kernel(
    const float* __restrict__ ms1_w, unsigned short* __restrict__ w_ms1,
    const float* __restrict__ ms2_w, unsigned short* __restrict__ w_ms2,
    const float* __restrict__ us1_w, unsigned short* __restrict__ w_us1,
    const float* __restrict__ us2_w, unsigned short* __restrict__ w_us2,
    const float* __restrict__ s,     unsigned short* __restrict__ sbf,
    const float* __restrict__ v,     us4* __restrict__ v4,
    const float* __restrict__ mv_w,  unsigned short* __restrict__ mvwB,
    const int* __restrict__ src, const int* __restrict__ dst,
    int* __restrict__ cursor, int* __restrict__ jbuf,
    int nF, int E)
{
  int i = blockIdx.x * 256 + threadIdx.x;
  if (i < 16384) w_ms1[i] = f2bf(ms1_w[i]);
  if (i < 49152) w_ms2[i] = f2bf(ms2_w[i]);
  if (i < 16384) w_us1[i] = f2bf(us1_w[i]);
  if (i < 49152) w_us2[i] = f2bf(us2_w[i]);
  if (i < nF)    sbf[i] = f2bf(s[i]);
  if (i < nF) {
    const float* vp = v + (size_t)i * 3;
    us4 o; o.x = f2bf(vp[0]); o.y = f2bf(vp[1]); o.z = f2bf(vp[2]); o.w = 0;
    v4[i] = o;
  }
  if (i < 384 * 32) {
    int o = i >> 5, k = i & 31;
    float val = (k < 20) ? mv_w[o * 20 + k] * 0.6324555320336759f : 0.f;
    mvwB[i] = f2bf(val);
  }
  if (i < E) {
    int d = dst[i];
    int p = atomicAdd(&cursor[d], 1);
    if (p < CAP) jbuf[d * CAP + p] = src[i];
  }
}

// ---------------------------------------------------------------------------
// Yc[n][f] (12B) = { (ssp(X@W1^T+b1)@W2^T+b2) triplet , Vin[n][f] triplet }
// one wave per block, 16 nodes per block.
__global__ __launch_bounds__(64) void mlp_kernel(
    const unsigned short* __restrict__ X,    // [n][128] bf16
    const unsigned short* __restrict__ W1,   // [128][128] bf16
    const float* __restrict__ B1,            // [128]
    const unsigned short* __restrict__ W2,   // [384][128] bf16
    const float* __restrict__ B2,            // [384]
    const us4* __restrict__ Vin,             // [n][128] bf16 triplet
    unsigned short* __restrict__ Yc)         // [n][128] 12B records
{
  __shared__ float HT[128 * 17];
  const int lane = threadIdx.x;
  const int c    = lane & 15;
  const int quad = lane >> 4;
  const int m0   = blockIdx.x * 16;

  f32x4 acc[8];
#pragma unroll
  for (int t = 0; t < 8; t++) acc[t] = (f32x4){0.f, 0.f, 0.f, 0.f};
#pragma unroll
  for (int kk = 0; kk < 4; kk++) {
    short8 a = *(const short8*)(X + (size_t)(m0 + c) * 128 + kk * 32 + quad * 8);
#pragma unroll
    for (int t = 0; t < 8; t++) {
      short8 b = *(const short8*)(W1 + (size_t)(t * 16 + c) * 128 + kk * 32 + quad * 8);
      acc[t] = __builtin_amdgcn_mfma_f32_16x16x32_bf16(a, b, acc[t], 0, 0, 0);
    }
  }
#pragma unroll
  for (int t = 0; t < 8; t++) {
    float bias = B1[t * 16 + c];
    int k = t * 16 + c;
#pragma unroll
    for (int r = 0; r < 4; r++) {
      float h = acc[t][r] + bias;
      float sp = (h > 15.f) ? h : log1pf(__expf(h));
      sp -= 0.69314718056f;
      HT[k * 17 + quad * 4 + r] = sp;
    }
  }
  __syncthreads();

  // all 24 output tiles resident so a full 12B record can be written at once
  f32x4 acc2[3][8];
#pragma unroll
  for (int g = 0; g < 3; g++)
#pragma unroll
    for (int t = 0; t < 8; t++) acc2[g][t] = (f32x4){0.f, 0.f, 0.f, 0.f};
#pragma unroll
  for (int kk = 0; kk < 4; kk++) {
    short8 afr;
#pragma unroll
    for (int j = 0; j < 8; j++) {
      float hv = HT[(kk * 32 + quad * 8 + j) * 17 + c];
      afr[j] = (short)f2bf(hv);
    }
#pragma unroll
    for (int g = 0; g < 3; g++)
#pragma unroll
      for (int t = 0; t < 8; t++) {
        short8 b = *(const short8*)(W2 + (size_t)(g * 128 + t * 16 + c) * 128 + kk * 32 + quad * 8);
        acc2[g][t] = __builtin_amdgcn_mfma_f32_16x16x32_bf16(afr, b, acc2[g][t], 0, 0, 0);
      }
  }
#pragma unroll
  for (int t = 0; t < 8; t++) {
    int f = t * 16 + c;                      // feature in [0,128)
    float b0 = B2[f], b1 = B2[128 + f], b2 = B2[256 + f];
#pragma unroll
    for (int r = 0; r < 4; r++) {
      int m = quad * 4 + r;
      us4 vv = Vin[(size_t)(m0 + m) * 128 + f];
      unsigned p0 = f2bf(acc2[0][t][r] + b0);
      unsigned p1 = f2bf(acc2[1][t][r] + b1);
      unsigned p2 = f2bf(acc2[2][t][r] + b2);
      u3 rec;
      rec.a = p0 | (p1 << 16);
      rec.b = p2 | ((unsigned)vv.x << 16);
      rec.c = (unsigned)vv.y | ((unsigned)vv.z << 16);
      *(u3*)(Yc + ((size_t)(m0 + m) * 128 + f) * 6) = rec;
    }
  }
}

// ---------------------------------------------------------------------------
// pass 1 (fused W-GEMM): block = 1 dst node, 4 waves = (half) x (parity).
// 16-edge batches; phase B prefetches all (<=8) gathers before consuming.
__global__ __launch_bounds__(256, 6) void pass1_kernel(
    const float* __restrict__ x,       // [N,3]
    const unsigned short* __restrict__ combo1, // [N,128] 12B {phi012,v012}
    const float* __restrict__ v,       // [N,128,3] fp32 (epilogue add)
    const float* __restrict__ s,       // [N,128]
    const unsigned short* __restrict__ mvwB,  // [384][32] bf16 scale-folded
    const float* __restrict__ mv_b,           // [384]
    const int* __restrict__ jbuf,      // [N,CAP] src ids
    const int* __restrict__ deg,
    float* __restrict__ vnew, us4* __restrict__ vnew4,
    float* __restrict__ snew, unsigned short* __restrict__ snew_bf, int nNodes)
{
  __shared__ unsigned short Asn[BATCH * 32];  // 1 KB  A-tile (bf16 sn rows)
  __shared__ float4 Au[BATCH];                // 256 B {u0,u1,u2,invr}
  __shared__ us4 Wl[BATCH * 128];             // 16 KB per-batch weight triplets
  __shared__ float red[512];                  // 2 KB  cross-wave reduction

  const int tid  = threadIdx.x;
  const int wave = tid >> 6, lane = tid & 63;
  const int half = wave >> 1, split = wave & 1;
  const int i = blockIdx.x;
  const int f = lane + 64 * half;             // feature in [0,128)
  const int c = lane & 15, quad = lane >> 4;

  int cnt = deg[i]; if (cnt > CAP) cnt = CAP;
  const int base = i * CAP;

  // B-frags + bias for this wave's 6 tiles: {2w,2w+1,2w+8,2w+9,2w+16,2w+17}
  short8 bfr[6]; float bias[6];
#pragma unroll
  for (int p = 0; p < 3; p++)
#pragma unroll
    for (int h = 0; h < 2; h++) {
      int t = 2 * wave + h + 8 * p;
      bfr[p * 2 + h]  = *(const short8*)(mvwB + (size_t)(t * 16 + c) * 32 + quad * 8);
      bias[p * 2 + h] = mv_b[t * 16 + c];
    }

  const float xi0 = x[i * 3], xi1 = x[i * 3 + 1], xi2 = x[i * 3 + 2];
  int jv = (lane < cnt) ? jbuf[base + lane] : 0;

  float accV0 = 0.f, accV1 = 0.f, accV2 = 0.f, accS = 0.f;

  for (int bs = 0; bs < cnt; bs += BATCH) {
    int bcnt = cnt - bs; if (bcnt > BATCH) bcnt = BATCH;
    __syncthreads();                           // previous batch fully consumed

    if (wave == 0) {
      // ALL 64 lanes execute the shfl (source lanes must be exec-active);
      // e = bs + (lane&15) <= 48+15 = 63, always a valid source lane.
      int t16 = lane & (BATCH - 1);
      int e = bs + t16;
      int j = __shfl(jv, e);
      if (lane < BATCH && e < cnt) {
        float d0 = x[j * 3]     - xi0;
        float d1 = x[j * 3 + 1] - xi1;
        float d2 = x[j * 3 + 2] - xi2;
        float r = sqrtf(d0 * d0 + d1 * d1 + d2 * d2 + 1e-5f);
        float invr = 1.0f / r;
        Au[lane] = make_float4(d0 * invr, d1 * invr, d2 * invr, invr);
        float theta = r * 0.6283185307179586f;
        float s1, c1;
        __sincosf(theta, &s1, &c1);
        float c2 = 2.f * c1;
        float pm2 = s1, pm1 = c2 * s1;
        Asn[lane * 32 + 0] = f2bf(pm2);
        Asn[lane * 32 + 1] = f2bf(pm1);
#pragma unroll
        for (int l = 2; l < L_DIM; l++) {
          float cur = c2 * pm1 - pm2;
          Asn[lane * 32 + l] = f2bf(cur);
          pm2 = pm1; pm1 = cur;
        }
#pragma unroll
        for (int l = L_DIM; l < 32; l++) Asn[lane * 32 + l] = 0;
      }
    }
    __syncthreads();

    // single 16-row MFMA group
    {
      short8 a = *(const short8*)&Asn[c * 32 + quad * 8];
      f32x4 acc[6];
#pragma unroll
      for (int q = 0; q < 6; q++)
        acc[q] = __builtin_amdgcn_mfma_f32_16x16x32_bf16(
            a, bfr[q], (f32x4){0.f, 0.f, 0.f, 0.f}, 0, 0, 0);
#pragma unroll
      for (int r = 0; r < 4; r++) {
        int el = quad * 4 + r;
        if (el < bcnt) {
          float invr = Au[el].w;
#pragma unroll
          for (int h = 0; h < 2; h++) {
            float wp0 = fmaf(acc[h][r],     invr, bias[h]);
            float wp1 = fmaf(acc[2 + h][r], invr, bias[2 + h]);
            float wp2 = fmaf(acc[4 + h][r], invr, bias[4 + h]);
            float w0 = (wp0 < 5.f) ? 0.5f * (__cosf(wp0 * 0.6283185307179586f) + 1.f) : 0.f;
            float w1 = (wp1 < 5.f) ? 0.5f * (__cosf(wp1 * 0.6283185307179586f) + 1.f) : 0.f;
            float w2 = (wp2 < 5.f) ? 0.5f * (__cosf(wp2 * 0.6283185307179586f) + 1.f) : 0.f;
            us4 o; o.x = f2bf(w0); o.y = f2bf(w1); o.z = f2bf(w2); o.w = 0;
            Wl[el * 128 + wave * 32 + h * 16 + c] = o;
          }
        }
      }
    }
    __syncthreads();

    // phase B: prefetch ALL gathers for this parity (<=8), then consume.
    // (shfl here is in wave-uniform control flow: all 64 lanes active.)
    u3 cb[8];
#pragma unroll
    for (int k = 0; k < 8; k++) {
      int e = split + 2 * k;
      if (e < bcnt) {
        int j = __shfl(jv, bs + e);
        cb[k] = *(const u3*)(combo1 + ((size_t)j * 128 + f) * 6);
      }
    }
#pragma unroll
    for (int k = 0; k < 8; k++) {
      int e = split + 2 * k;
      if (e < bcnt) {
        float4 u = Au[e];
        us4 wv = Wl[e * 128 + f];
        float ph0 = bf2f((unsigned short)(cb[k].a & 0xffff));
        float ph1 = bf2f((unsigned short)(cb[k].a >> 16));
        float ph2 = bf2f((unsigned short)(cb[k].b & 0xffff));
        float vx  = bf2f((unsigned short)(cb[k].b >> 16));
        float vy  = bf2f((unsigned short)(cb[k].c & 0xffff));
        float vz  = bf2f((unsigned short)(cb[k].c >> 16));
        float m0 = ph0 * bf2f(wv.x);
        float m1 = ph1 * bf2f(wv.y);
        float m2 = ph2 * bf2f(wv.z);
        accV0 = fmaf(vx, m0, fmaf(m2, u.x, accV0));
        accV1 = fmaf(vy, m0, fmaf(m2, u.y, accV1));
        accV2 = fmaf(vz, m0, fmaf(m2, u.z, accV2));
        accS += m1;
      }
    }
  }

  const int idx = half * 64 + lane;
  __syncthreads();
  if (split == 1) {
    red[idx * 4 + 0] = accV0; red[idx * 4 + 1] = accV1;
    red[idx * 4 + 2] = accV2; red[idx * 4 + 3] = accS;
  }
  __syncthreads();
  if (split == 0) {
    accV0 += red[idx * 4 + 0]; accV1 += red[idx * 4 + 1];
    accV2 += red[idx * 4 + 2]; accS  += red[idx * 4 + 3];
    size_t b3 = (size_t)i * 384 + f * 3;
    float n0 = v[b3] + accV0, n1 = v[b3 + 1] + accV1, n2 = v[b3 + 2] + accV2;
    vnew[b3] = n0; vnew[b3 + 1] = n1; vnew[b3 + 2] = n2;
    us4 o; o.x = f2bf(n0); o.y = f2bf(n1); o.z = f2bf(n2); o.w = 0;
    vnew4[(size_t)i * 128 + f] = o;
    size_t b1 = (size_t)i * 128 + f;
    float sv = s[b1] + accS;
    snew[b1] = sv;
    snew_bf[b1] = f2bf(sv);
  }
}

// ---------------------------------------------------------------------------
// pass 2: block = 1 dst node, 4 waves = (feature half) x (edge parity).
// chunked (8-edge) prefetch; shfl sits in wave-uniform control flow.
__global__ __launch_bounds__(256, 8) void pass2_kernel(
    const float* __restrict__ vnew,   // [N,128,3] fp32
    const float* __restrict__ snew,   // [N,128]
    const unsigned short* __restrict__ combo2, // [N,128] 12B {s2 012, vnew 012}
    const int* __restrict__ jbuf, const int* __restrict__ deg,
    float* __restrict__ vout, float* __restrict__ sout, int nNodes)
{
  __shared__ float red[1024];
  const int wave = threadIdx.x >> 6, lane = threadIdx.x & 63;
  const int half = wave >> 1, split = wave & 1;
  const int i = blockIdx.x;
  const int f = lane + 64 * half;

  int cnt = deg[i]; if (cnt > CAP) cnt = CAP;
  const int base = i * CAP;
  int jv = (lane < cnt) ? jbuf[base + lane] : 0;

  float accU0 = 0.f, accU1 = 0.f, accU2 = 0.f;
  float accM0 = 0.f, accM1 = 0.f, accM2 = 0.f;

  for (int b0 = split; b0 < cnt; b0 += 16) {
    u3 cb[8];
#pragma unroll
    for (int k = 0; k < 8; k++) {
      int e = b0 + 2 * k;
      if (e < cnt) {
        int j = __shfl(jv, e);
        cb[k] = *(const u3*)(combo2 + ((size_t)j * 128 + f) * 6);
      }
    }
#pragma unroll
    for (int k = 0; k < 8; k++) {
      int e = b0 + 2 * k;
      if (e < cnt) {
        accM0 += bf2f((unsigned short)(cb[k].a & 0xffff));
        accM1 += bf2f((unsigned short)(cb[k].a >> 16));
        accM2 += bf2f((unsigned short)(cb[k].b & 0xffff));
        accU0 += bf2f((unsigned short)(cb[k].b >> 16));
        accU1 += bf2f((unsigned short)(cb[k].c & 0xffff));
        accU2 += bf2f((unsigned short)(cb[k].c >> 16));
      }
    }
  }

  const int idx = half * 64 + lane;
  if (split == 1) {
    red[idx * 8 + 0] = accU0; red[idx * 8 + 1] = accU1; red[idx * 8 + 2] = accU2;
    red[idx * 8 + 3] = accM0; red[idx * 8 + 4] = accM1; red[idx * 8 + 5] = accM2;
  }
  __syncthreads();
  if (split == 0) {
    accU0 += red[idx * 8 + 0]; accU1 += red[idx * 8 + 1]; accU2 += red[idx * 8 + 2];
    accM0 += red[idx * 8 + 3]; accM1 += red[idx * 8 + 4]; accM2 += red[idx * 8 + 5];

    float dinv = 1.0f / (float)(cnt > 0 ? cnt : 1);
    float uv0 = accU0 * dinv, uv1 = accU1 * dinv, uv2 = accU2 * dinv;
    float avv = accM0 * dinv, asv = accM1 * dinv, ass = accM2 * dinv;
    float q = uv0 * uv0 + uv1 * uv1 + uv2 * uv2;
    float ds2 = (q / (q + 1e-5f)) * asv + ass;
    size_t b3 = (size_t)i * 384 + f * 3;
    vout[b3]     = vnew[b3]     + uv0 * avv;
    vout[b3 + 1] = vnew[b3 + 1] + uv1 * avv;
    vout[b3 + 2] = vnew[b3 + 2] + uv2 * avv;
    size_t b1 = (size_t)i * 128 + f;
    sout[b1] = snew[b1] + ds2;
  }
}

// ---------------------------------------------------------------------------
extern "C" void kernel_launch(void* const* d_in, const int* in_sizes, int n_in,
                              void* d_out, int out_size, void* d_ws, size_t ws_size,
                              hipStream_t stream)
{
  const float* x     = (const float*)d_in[0];
  const float* v     = (const float*)d_in[1];
  const float* s     = (const float*)d_in[2];
  const float* ms1_w = (const float*)d_in[3];
  const float* ms1_b = (const float*)d_in[4];
  const float* ms2_w = (const float*)d_in[5];
  const float* ms2_b = (const float*)d_in[6];
  const float* mv_w  = (const float*)d_in[7];
  const float* mv_b  = (const float*)d_in[8];
  const float* us1_w = (const float*)d_in[9];
  const float* us1_b = (const float*)d_in[10];
  const float* us2_w = (const float*)d_in[11];
  const float* us2_b = (const float*)d_in[12];
  const int*   src   = (const int*)d_in[13];
  const int*   dst   = (const int*)d_in[14];

  const int N = in_sizes[0] / 3;        // 10000
  const int E = in_sizes[13];           // 100000

  char* p = (char*)d_ws;
  auto alloc = [&](size_t bytes) -> void* {
    void* r = (void*)p;
    p += (bytes + 255) & ~(size_t)255;
    return r;
  };
  unsigned short* sbf   = (unsigned short*)alloc((size_t)N * 128 * 2);
  unsigned short* snbf  = (unsigned short*)alloc((size_t)N * 128 * 2);
  unsigned short* w_ms1 = (unsigned short*)alloc(16384 * 2);
  unsigned short* w_ms2 = (unsigned short*)alloc(49152 * 2);
  unsigned short* w_us1 = (unsigned short*)alloc(16384 * 2);
  unsigned short* w_us2 = (unsigned short*)alloc(49152 * 2);
  unsigned short* mvwB  = (unsigned short*)alloc(384 * 32 * 2);
  us4*   v4     = (us4*)alloc((size_t)N * 128 * 8);
  us4*   vnew4  = (us4*)alloc((size_t)N * 128 * 8);
  unsigned short* combo1 = (unsigned short*)alloc((size_t)N * 128 * 12);
  unsigned short* combo2 = (unsigned short*)alloc((size_t)N * 128 * 12);
  float* vnew   = (float*)alloc((size_t)N * 384 * 4);
  float* snew   = (float*)alloc((size_t)N * 128 * 4);
  int* cursor   = (int*)alloc((size_t)N * 4);           // becomes deg after fill
  int* jbuf     = (int*)alloc((size_t)N * CAP * 4);

  hipMemsetAsync(cursor, 0, (size_t)N * 4, stream);

  cast_fill_kernel<<<(N * 128 + 255) / 256, 256, 0, stream>>>(
      ms1_w, w_ms1, ms2_w, w_ms2, us1_w, w_us1, us2_w, w_us2,
      s, sbf, v, v4, mv_w, mvwB, src, dst, cursor, jbuf, N * 128, E);

  // combo1 = {phi triplet, v triplet}
  mlp_kernel<<<N / 16, 64, 0, stream>>>(sbf, w_ms1, ms1_b, w_ms2, ms2_b,
                                        v4, combo1);

  pass1_kernel<<<N, 256, 0, stream>>>(x, combo1, v, s, mvwB, mv_b,
                                      jbuf, cursor, vnew, vnew4, snew, snbf, N);

  // combo2 = {s2 triplet, vnew triplet}
  mlp_kernel<<<N / 16, 64, 0, stream>>>(snbf, w_us1, us1_b, w_us2, us2_b,
                                        vnew4, combo2);

  float* vout = (float*)d_out;
  float* sout = vout + (size_t)N * 384;
  pass2_kernel<<<N, 256, 0, stream>>>(vnew, snew, combo2, jbuf, cursor,
                                      vout, sout, N);
}

// Round 10
// 263.346 us; speedup vs baseline: 1.4455x; 1.4455x over previous
//
#include <hip/hip_runtime.h>
#include <hip/hip_bf16.h>

// TMDConv (PaiNN/TorchMD-style) two-pass message passing on MI355X.
// R10 = R9 with ONE change: pass1 __launch_bounds__(256,6) -> (256,4).
//   R9 evidence: the 6-waves/EU bound caps VGPRs at ~85; the body (bfr[6]
//   short8=24 + bias 6 + cb[8]=24 + acc/addressing) needs ~90+, so the
//   compiler spilled to scratch -> WRITE_SIZE 32.5->627 MB, FETCH 74->303 MB,
//   pass1 65->200 us. At 4 waves/EU (128 VGPR cap) everything fits; 20 KB
//   LDS still allows 4 blocks/CU (~50% occ, up from R7's 35%).

#define F_DIM   128
#define F3_DIM  384
#define L_DIM   20
#define CAP     64          // max in-degree bucket capacity
#define BATCH   16

typedef __attribute__((ext_vector_type(8))) short short8;
typedef __attribute__((ext_vector_type(4))) float f32x4;
typedef __attribute__((ext_vector_type(4))) unsigned short us4;

struct u3 { unsigned a, b, c; };   // 12B record (dwordx3)

__device__ __forceinline__ unsigned short f2bf(float f) {
  union { float f; unsigned u; } a; a.f = f;
  unsigned u = a.u;
  u = (u + 0x7FFFu + ((u >> 16) & 1u)) >> 16;   // RNE
  return (unsigned short)u;
}
__device__ __forceinline__ float bf2f(unsigned short u) {
  union { unsigned u; float f; } a; a.u = ((unsigned)u) << 16;
  return a.f;
}

// ---------------------------------------------------------------------------
// fused cast+fill kernel
__global__ __launch_bounds__(256) void cast_fill_kernel(
    const float* __restrict__ ms1_w, unsigned short* __restrict__ w_ms1,
    const float* __restrict__ ms2_w, unsigned short* __restrict__ w_ms2,
    const float* __restrict__ us1_w, unsigned short* __restrict__ w_us1,
    const float* __restrict__ us2_w, unsigned short* __restrict__ w_us2,
    const float* __restrict__ s,     unsigned short* __restrict__ sbf,
    const float* __restrict__ v,     us4* __restrict__ v4,
    const float* __restrict__ mv_w,  unsigned short* __restrict__ mvwB,
    const int* __restrict__ src, const int* __restrict__ dst,
    int* __restrict__ cursor, int* __restrict__ jbuf,
    int nF, int E)
{
  int i = blockIdx.x * 256 + threadIdx.x;
  if (i < 16384) w_ms1[i] = f2bf(ms1_w[i]);
  if (i < 49152) w_ms2[i] = f2bf(ms2_w[i]);
  if (i < 16384) w_us1[i] = f2bf(us1_w[i]);
  if (i < 49152) w_us2[i] = f2bf(us2_w[i]);
  if (i < nF)    sbf[i] = f2bf(s[i]);
  if (i < nF) {
    const float* vp = v + (size_t)i * 3;
    us4 o; o.x = f2bf(vp[0]); o.y = f2bf(vp[1]); o.z = f2bf(vp[2]); o.w = 0;
    v4[i] = o;
  }
  if (i < 384 * 32) {
    int o = i >> 5, k = i & 31;
    float val = (k < 20) ? mv_w[o * 20 + k] * 0.6324555320336759f : 0.f;
    mvwB[i] = f2bf(val);
  }
  if (i < E) {
    int d = dst[i];
    int p = atomicAdd(&cursor[d], 1);
    if (p < CAP) jbuf[d * CAP + p] = src[i];
  }
}

// ---------------------------------------------------------------------------
// Yc[n][f] (12B) = { (ssp(X@W1^T+b1)@W2^T+b2) triplet , Vin[n][f] triplet }
// one wave per block, 16 nodes per block.
__global__ __launch_bounds__(64) void mlp_kernel(
    const unsigned short* __restrict__ X,    // [n][128] bf16
    const unsigned short* __restrict__ W1,   // [128][128] bf16
    const float* __restrict__ B1,            // [128]
    const unsigned short* __restrict__ W2,   // [384][128] bf16
    const float* __restrict__ B2,            // [384]
    const us4* __restrict__ Vin,             // [n][128] bf16 triplet
    unsigned short* __restrict__ Yc)         // [n][128] 12B records
{
  __shared__ float HT[128 * 17];
  const int lane = threadIdx.x;
  const int c    = lane & 15;
  const int quad = lane >> 4;
  const int m0   = blockIdx.x * 16;

  f32x4 acc[8];
#pragma unroll
  for (int t = 0; t < 8; t++) acc[t] = (f32x4){0.f, 0.f, 0.f, 0.f};
#pragma unroll
  for (int kk = 0; kk < 4; kk++) {
    short8 a = *(const short8*)(X + (size_t)(m0 + c) * 128 + kk * 32 + quad * 8);
#pragma unroll
    for (int t = 0; t < 8; t++) {
      short8 b = *(const short8*)(W1 + (size_t)(t * 16 + c) * 128 + kk * 32 + quad * 8);
      acc[t] = __builtin_amdgcn_mfma_f32_16x16x32_bf16(a, b, acc[t], 0, 0, 0);
    }
  }
#pragma unroll
  for (int t = 0; t < 8; t++) {
    float bias = B1[t * 16 + c];
    int k = t * 16 + c;
#pragma unroll
    for (int r = 0; r < 4; r++) {
      float h = acc[t][r] + bias;
      float sp = (h > 15.f) ? h : log1pf(__expf(h));
      sp -= 0.69314718056f;
      HT[k * 17 + quad * 4 + r] = sp;
    }
  }
  __syncthreads();

  // all 24 output tiles resident so a full 12B record can be written at once
  f32x4 acc2[3][8];
#pragma unroll
  for (int g = 0; g < 3; g++)
#pragma unroll
    for (int t = 0; t < 8; t++) acc2[g][t] = (f32x4){0.f, 0.f, 0.f, 0.f};
#pragma unroll
  for (int kk = 0; kk < 4; kk++) {
    short8 afr;
#pragma unroll
    for (int j = 0; j < 8; j++) {
      float hv = HT[(kk * 32 + quad * 8 + j) * 17 + c];
      afr[j] = (short)f2bf(hv);
    }
#pragma unroll
    for (int g = 0; g < 3; g++)
#pragma unroll
      for (int t = 0; t < 8; t++) {
        short8 b = *(const short8*)(W2 + (size_t)(g * 128 + t * 16 + c) * 128 + kk * 32 + quad * 8);
        acc2[g][t] = __builtin_amdgcn_mfma_f32_16x16x32_bf16(afr, b, acc2[g][t], 0, 0, 0);
      }
  }
#pragma unroll
  for (int t = 0; t < 8; t++) {
    int f = t * 16 + c;                      // feature in [0,128)
    float b0 = B2[f], b1 = B2[128 + f], b2 = B2[256 + f];
#pragma unroll
    for (int r = 0; r < 4; r++) {
      int m = quad * 4 + r;
      us4 vv = Vin[(size_t)(m0 + m) * 128 + f];
      unsigned p0 = f2bf(acc2[0][t][r] + b0);
      unsigned p1 = f2bf(acc2[1][t][r] + b1);
      unsigned p2 = f2bf(acc2[2][t][r] + b2);
      u3 rec;
      rec.a = p0 | (p1 << 16);
      rec.b = p2 | ((unsigned)vv.x << 16);
      rec.c = (unsigned)vv.y | ((unsigned)vv.z << 16);
      *(u3*)(Yc + ((size_t)(m0 + m) * 128 + f) * 6) = rec;
    }
  }
}

// ---------------------------------------------------------------------------
// pass 1 (fused W-GEMM): block = 1 dst node, 4 waves = (half) x (parity).
// 16-edge batches; phase B prefetches all (<=8) gathers before consuming.
__global__ __launch_bounds__(256, 4) void pass1_kernel(
    const float* __restrict__ x,       // [N,3]
    const unsigned short* __restrict__ combo1, // [N,128] 12B {phi012,v012}
    const float* __restrict__ v,       // [N,128,3] fp32 (epilogue add)
    const float* __restrict__ s,       // [N,128]
    const unsigned short* __restrict__ mvwB,  // [384][32] bf16 scale-folded
    const float* __restrict__ mv_b,           // [384]
    const int* __restrict__ jbuf,      // [N,CAP] src ids
    const int* __restrict__ deg,
    float* __restrict__ vnew, us4* __restrict__ vnew4,
    float* __restrict__ snew, unsigned short* __restrict__ snew_bf, int nNodes)
{
  __shared__ unsigned short Asn[BATCH * 32];  // 1 KB  A-tile (bf16 sn rows)
  __shared__ float4 Au[BATCH];                // 256 B {u0,u1,u2,invr}
  __shared__ us4 Wl[BATCH * 128];             // 16 KB per-batch weight triplets
  __shared__ float red[512];                  // 2 KB  cross-wave reduction

  const int tid  = threadIdx.x;
  const int wave = tid >> 6, lane = tid & 63;
  const int half = wave >> 1, split = wave & 1;
  const int i = blockIdx.x;
  const int f = lane + 64 * half;             // feature in [0,128)
  const int c = lane & 15, quad = lane >> 4;

  int cnt = deg[i]; if (cnt > CAP) cnt = CAP;
  const int base = i * CAP;

  // B-frags + bias for this wave's 6 tiles: {2w,2w+1,2w+8,2w+9,2w+16,2w+17}
  short8 bfr[6]; float bias[6];
#pragma unroll
  for (int p = 0; p < 3; p++)
#pragma unroll
    for (int h = 0; h < 2; h++) {
      int t = 2 * wave + h + 8 * p;
      bfr[p * 2 + h]  = *(const short8*)(mvwB + (size_t)(t * 16 + c) * 32 + quad * 8);
      bias[p * 2 + h] = mv_b[t * 16 + c];
    }

  const float xi0 = x[i * 3], xi1 = x[i * 3 + 1], xi2 = x[i * 3 + 2];
  int jv = (lane < cnt) ? jbuf[base + lane] : 0;

  float accV0 = 0.f, accV1 = 0.f, accV2 = 0.f, accS = 0.f;

  for (int bs = 0; bs < cnt; bs += BATCH) {
    int bcnt = cnt - bs; if (bcnt > BATCH) bcnt = BATCH;
    __syncthreads();                           // previous batch fully consumed

    if (wave == 0) {
      // ALL 64 lanes execute the shfl (source lanes must be exec-active);
      // e = bs + (lane&15) <= 48+15 = 63, always a valid source lane.
      int t16 = lane & (BATCH - 1);
      int e = bs + t16;
      int j = __shfl(jv, e);
      if (lane < BATCH && e < cnt) {
        float d0 = x[j * 3]     - xi0;
        float d1 = x[j * 3 + 1] - xi1;
        float d2 = x[j * 3 + 2] - xi2;
        float r = sqrtf(d0 * d0 + d1 * d1 + d2 * d2 + 1e-5f);
        float invr = 1.0f / r;
        Au[lane] = make_float4(d0 * invr, d1 * invr, d2 * invr, invr);
        float theta = r * 0.6283185307179586f;
        float s1, c1;
        __sincosf(theta, &s1, &c1);
        float c2 = 2.f * c1;
        float pm2 = s1, pm1 = c2 * s1;
        Asn[lane * 32 + 0] = f2bf(pm2);
        Asn[lane * 32 + 1] = f2bf(pm1);
#pragma unroll
        for (int l = 2; l < L_DIM; l++) {
          float cur = c2 * pm1 - pm2;
          Asn[lane * 32 + l] = f2bf(cur);
          pm2 = pm1; pm1 = cur;
        }
#pragma unroll
        for (int l = L_DIM; l < 32; l++) Asn[lane * 32 + l] = 0;
      }
    }
    __syncthreads();

    // single 16-row MFMA group
    {
      short8 a = *(const short8*)&Asn[c * 32 + quad * 8];
      f32x4 acc[6];
#pragma unroll
      for (int q = 0; q < 6; q++)
        acc[q] = __builtin_amdgcn_mfma_f32_16x16x32_bf16(
            a, bfr[q], (f32x4){0.f, 0.f, 0.f, 0.f}, 0, 0, 0);
#pragma unroll
      for (int r = 0; r < 4; r++) {
        int el = quad * 4 + r;
        if (el < bcnt) {
          float invr = Au[el].w;
#pragma unroll
          for (int h = 0; h < 2; h++) {
            float wp0 = fmaf(acc[h][r],     invr, bias[h]);
            float wp1 = fmaf(acc[2 + h][r], invr, bias[2 + h]);
            float wp2 = fmaf(acc[4 + h][r], invr, bias[4 + h]);
            float w0 = (wp0 < 5.f) ? 0.5f * (__cosf(wp0 * 0.6283185307179586f) + 1.f) : 0.f;
            float w1 = (wp1 < 5.f) ? 0.5f * (__cosf(wp1 * 0.6283185307179586f) + 1.f) : 0.f;
            float w2 = (wp2 < 5.f) ? 0.5f * (__cosf(wp2 * 0.6283185307179586f) + 1.f) : 0.f;
            us4 o; o.x = f2bf(w0); o.y = f2bf(w1); o.z = f2bf(w2); o.w = 0;
            Wl[el * 128 + wave * 32 + h * 16 + c] = o;
          }
        }
      }
    }
    __syncthreads();

    // phase B: prefetch ALL gathers for this parity (<=8), then consume.
    // (shfl here is in wave-uniform control flow: all 64 lanes active.)
    u3 cb[8];
#pragma unroll
    for (int k = 0; k < 8; k++) {
      int e = split + 2 * k;
      if (e < bcnt) {
        int j = __shfl(jv, bs + e);
        cb[k] = *(const u3*)(combo1 + ((size_t)j * 128 + f) * 6);
      }
    }
#pragma unroll
    for (int k = 0; k < 8; k++) {
      int e = split + 2 * k;
      if (e < bcnt) {
        float4 u = Au[e];
        us4 wv = Wl[e * 128 + f];
        float ph0 = bf2f((unsigned short)(cb[k].a & 0xffff));
        float ph1 = bf2f((unsigned short)(cb[k].a >> 16));
        float ph2 = bf2f((unsigned short)(cb[k].b & 0xffff));
        float vx  = bf2f((unsigned short)(cb[k].b >> 16));
        float vy  = bf2f((unsigned short)(cb[k].c & 0xffff));
        float vz  = bf2f((unsigned short)(cb[k].c >> 16));
        float m0 = ph0 * bf2f(wv.x);
        float m1 = ph1 * bf2f(wv.y);
        float m2 = ph2 * bf2f(wv.z);
        accV0 = fmaf(vx, m0, fmaf(m2, u.x, accV0));
        accV1 = fmaf(vy, m0, fmaf(m2, u.y, accV1));
        accV2 = fmaf(vz, m0, fmaf(m2, u.z, accV2));
        accS += m1;
      }
    }
  }

  const int idx = half * 64 + lane;
  __syncthreads();
  if (split == 1) {
    red[idx * 4 + 0] = accV0; red[idx * 4 + 1] = accV1;
    red[idx * 4 + 2] = accV2; red[idx * 4 + 3] = accS;
  }
  __syncthreads();
  if (split == 0) {
    accV0 += red[idx * 4 + 0]; accV1 += red[idx * 4 + 1];
    accV2 += red[idx * 4 + 2]; accS  += red[idx * 4 + 3];
    size_t b3 = (size_t)i * 384 + f * 3;
    float n0 = v[b3] + accV0, n1 = v[b3 + 1] + accV1, n2 = v[b3 + 2] + accV2;
    vnew[b3] = n0; vnew[b3 + 1] = n1; vnew[b3 + 2] = n2;
    us4 o; o.x = f2bf(n0); o.y = f2bf(n1); o.z = f2bf(n2); o.w = 0;
    vnew4[(size_t)i * 128 + f] = o;
    size_t b1 = (size_t)i * 128 + f;
    float sv = s[b1] + accS;
    snew[b1] = sv;
    snew_bf[b1] = f2bf(sv);
  }
}

// ---------------------------------------------------------------------------
// pass 2: block = 1 dst node, 4 waves = (feature half) x (edge parity).
// chunked (8-edge) prefetch; shfl sits in wave-uniform control flow.
__global__ __launch_bounds__(256, 8) void pass2_kernel(
    const float* __restrict__ vnew,   // [N,128,3] fp32
    const float* __restrict__ snew,   // [N,128]
    const unsigned short* __restrict__ combo2, // [N,128] 12B {s2 012, vnew 012}
    const int* __restrict__ jbuf, const int* __restrict__ deg,
    float* __restrict__ vout, float* __restrict__ sout, int nNodes)
{
  __shared__ float red[1024];
  const int wave = threadIdx.x >> 6, lane = threadIdx.x & 63;
  const int half = wave >> 1, split = wave & 1;
  const int i = blockIdx.x;
  const int f = lane + 64 * half;

  int cnt = deg[i]; if (cnt > CAP) cnt = CAP;
  const int base = i * CAP;
  int jv = (lane < cnt) ? jbuf[base + lane] : 0;

  float accU0 = 0.f, accU1 = 0.f, accU2 = 0.f;
  float accM0 = 0.f, accM1 = 0.f, accM2 = 0.f;

  for (int b0 = split; b0 < cnt; b0 += 16) {
    u3 cb[8];
#pragma unroll
    for (int k = 0; k < 8; k++) {
      int e = b0 + 2 * k;
      if (e < cnt) {
        int j = __shfl(jv, e);
        cb[k] = *(const u3*)(combo2 + ((size_t)j * 128 + f) * 6);
      }
    }
#pragma unroll
    for (int k = 0; k < 8; k++) {
      int e = b0 + 2 * k;
      if (e < cnt) {
        accM0 += bf2f((unsigned short)(cb[k].a & 0xffff));
        accM1 += bf2f((unsigned short)(cb[k].a >> 16));
        accM2 += bf2f((unsigned short)(cb[k].b & 0xffff));
        accU0 += bf2f((unsigned short)(cb[k].b >> 16));
        accU1 += bf2f((unsigned short)(cb[k].c & 0xffff));
        accU2 += bf2f((unsigned short)(cb[k].c >> 16));
      }
    }
  }

  const int idx = half * 64 + lane;
  if (split == 1) {
    red[idx * 8 + 0] = accU0; red[idx * 8 + 1] = accU1; red[idx * 8 + 2] = accU2;
    red[idx * 8 + 3] = accM0; red[idx * 8 + 4] = accM1; red[idx * 8 + 5] = accM2;
  }
  __syncthreads();
  if (split == 0) {
    accU0 += red[idx * 8 + 0]; accU1 += red[idx * 8 + 1]; accU2 += red[idx * 8 + 2];
    accM0 += red[idx * 8 + 3]; accM1 += red[idx * 8 + 4]; accM2 += red[idx * 8 + 5];

    float dinv = 1.0f / (float)(cnt > 0 ? cnt : 1);
    float uv0 = accU0 * dinv, uv1 = accU1 * dinv, uv2 = accU2 * dinv;
    float avv = accM0 * dinv, asv = accM1 * dinv, ass = accM2 * dinv;
    float q = uv0 * uv0 + uv1 * uv1 + uv2 * uv2;
    float ds2 = (q / (q + 1e-5f)) * asv + ass;
    size_t b3 = (size_t)i * 384 + f * 3;
    vout[b3]     = vnew[b3]     + uv0 * avv;
    vout[b3 + 1] = vnew[b3 + 1] + uv1 * avv;
    vout[b3 + 2] = vnew[b3 + 2] + uv2 * avv;
    size_t b1 = (size_t)i * 128 + f;
    sout[b1] = snew[b1] + ds2;
  }
}

// ---------------------------------------------------------------------------
extern "C" void kernel_launch(void* const* d_in, const int* in_sizes, int n_in,
                              void* d_out, int out_size, void* d_ws, size_t ws_size,
                              hipStream_t stream)
{
  const float* x     = (const float*)d_in[0];
  const float* v     = (const float*)d_in[1];
  const float* s     = (const float*)d_in[2];
  const float* ms1_w = (const float*)d_in[3];
  const float* ms1_b = (const float*)d_in[4];
  const float* ms2_w = (const float*)d_in[5];
  const float* ms2_b = (const float*)d_in[6];
  const float* mv_w  = (const float*)d_in[7];
  const float* mv_b  = (const float*)d_in[8];
  const float* us1_w = (const float*)d_in[9];
  const float* us1_b = (const float*)d_in[10];
  const float* us2_w = (const float*)d_in[11];
  const float* us2_b = (const float*)d_in[12];
  const int*   src   = (const int*)d_in[13];
  const int*   dst   = (const int*)d_in[14];

  const int N = in_sizes[0] / 3;        // 10000
  const int E = in_sizes[13];           // 100000

  char* p = (char*)d_ws;
  auto alloc = [&](size_t bytes) -> void* {
    void* r = (void*)p;
    p += (bytes + 255) & ~(size_t)255;
    return r;
  };
  unsigned short* sbf   = (unsigned short*)alloc((size_t)N * 128 * 2);
  unsigned short* snbf  = (unsigned short*)alloc((size_t)N * 128 * 2);
  unsigned short* w_ms1 = (unsigned short*)alloc(16384 * 2);
  unsigned short* w_ms2 = (unsigned short*)alloc(49152 * 2);
  unsigned short* w_us1 = (unsigned short*)alloc(16384 * 2);
  unsigned short* w_us2 = (unsigned short*)alloc(49152 * 2);
  unsigned short* mvwB  = (unsigned short*)alloc(384 * 32 * 2);
  us4*   v4     = (us4*)alloc((size_t)N * 128 * 8);
  us4*   vnew4  = (us4*)alloc((size_t)N * 128 * 8);
  unsigned short* combo1 = (unsigned short*)alloc((size_t)N * 128 * 12);
  unsigned short* combo2 = (unsigned short*)alloc((size_t)N * 128 * 12);
  float* vnew   = (float*)alloc((size_t)N * 384 * 4);
  float* snew   = (float*)alloc((size_t)N * 128 * 4);
  int* cursor   = (int*)alloc((size_t)N * 4);           // becomes deg after fill
  int* jbuf     = (int*)alloc((size_t)N * CAP * 4);

  hipMemsetAsync(cursor, 0, (size_t)N * 4, stream);

  cast_fill_kernel<<<(N * 128 + 255) / 256, 256, 0, stream>>>(
      ms1_w, w_ms1, ms2_w, w_ms2, us1_w, w_us1, us2_w, w_us2,
      s, sbf, v, v4, mv_w, mvwB, src, dst, cursor, jbuf, N * 128, E);

  // combo1 = {phi triplet, v triplet}
  mlp_kernel<<<N / 16, 64, 0, stream>>>(sbf, w_ms1, ms1_b, w_ms2, ms2_b,
                                        v4, combo1);

  pass1_kernel<<<N, 256, 0, stream>>>(x, combo1, v, s, mvwB, mv_b,
                                      jbuf, cursor, vnew, vnew4, snew, snbf, N);

  // combo2 = {s2 triplet, vnew triplet}
  mlp_kernel<<<N / 16, 64, 0, stream>>>(snbf, w_us1, us1_b, w_us2, us2_b,
                                        vnew4, combo2);

  float* vout = (float*)d_out;
  float* sout = vout + (size_t)N * 384;
  pass2_kernel<<<N, 256, 0, stream>>>(vnew, snew, combo2, jbuf, cursor,
                                      vout, sout, N);
}

// Round 11
// 241.406 us; speedup vs baseline: 1.5769x; 1.0909x over previous
//
#include <hip/hip_runtime.h>
#include <hip/hip_bf16.h>

// TMDConv (PaiNN/TorchMD-style) two-pass message passing on MI355X.
// R11 changes vs R10 (R10 evidence: pass1 WRITE 96.8 MB vs 33 MB legitimate
// -> ~64 MB scratch traffic persists even at VGPR 64 / cap 128):
//  - Theory: cb[8] is a private array with CONDITIONALLY-written elements
//    (if (e<bcnt) cb[k]=load) -> LLVM demotes it to scratch. Fix: clamp the
//    index (always-valid), load UNCONDITIONALLY, apply validity as a float
//    mask in the accumulate. Unconditional defs -> registers.
//  - pass2 had the same pattern PLUS launch_bounds(256,8) (64-VGPR cap) ->
//    likely the invisible chunk of the stable ~183us "rest". Same fix +
//    bound relaxed to (256,4).

#define F_DIM   128
#define F3_DIM  384
#define L_DIM   20
#define CAP     64          // max in-degree bucket capacity
#define BATCH   16

typedef __attribute__((ext_vector_type(8))) short short8;
typedef __attribute__((ext_vector_type(4))) float f32x4;
typedef __attribute__((ext_vector_type(4))) unsigned short us4;

struct u3 { unsigned a, b, c; };   // 12B record (dwordx3)

__device__ __forceinline__ unsigned short f2bf(float f) {
  union { float f; unsigned u; } a; a.f = f;
  unsigned u = a.u;
  u = (u + 0x7FFFu + ((u >> 16) & 1u)) >> 16;   // RNE
  return (unsigned short)u;
}
__device__ __forceinline__ float bf2f(unsigned short u) {
  union { unsigned u; float f; } a; a.u = ((unsigned)u) << 16;
  return a.f;
}

// ---------------------------------------------------------------------------
// fused cast+fill kernel
__global__ __launch_bounds__(256) void cast_fill_kernel(
    const float* __restrict__ ms1_w, unsigned short* __restrict__ w_ms1,
    const float* __restrict__ ms2_w, unsigned short* __restrict__ w_ms2,
    const float* __restrict__ us1_w, unsigned short* __restrict__ w_us1,
    const float* __restrict__ us2_w, unsigned short* __restrict__ w_us2,
    const float* __restrict__ s,     unsigned short* __restrict__ sbf,
    const float* __restrict__ v,     us4* __restrict__ v4,
    const float* __restrict__ mv_w,  unsigned short* __restrict__ mvwB,
    const int* __restrict__ src, const int* __restrict__ dst,
    int* __restrict__ cursor, int* __restrict__ jbuf,
    int nF, int E)
{
  int i = blockIdx.x * 256 + threadIdx.x;
  if (i < 16384) w_ms1[i] = f2bf(ms1_w[i]);
  if (i < 49152) w_ms2[i] = f2bf(ms2_w[i]);
  if (i < 16384) w_us1[i] = f2bf(us1_w[i]);
  if (i < 49152) w_us2[i] = f2bf(us2_w[i]);
  if (i < nF)    sbf[i] = f2bf(s[i]);
  if (i < nF) {
    const float* vp = v + (size_t)i * 3;
    us4 o; o.x = f2bf(vp[0]); o.y = f2bf(vp[1]); o.z = f2bf(vp[2]); o.w = 0;
    v4[i] = o;
  }
  if (i < 384 * 32) {
    int o = i >> 5, k = i & 31;
    float val = (k < 20) ? mv_w[o * 20 + k] * 0.6324555320336759f : 0.f;
    mvwB[i] = f2bf(val);
  }
  if (i < E) {
    int d = dst[i];
    int p = atomicAdd(&cursor[d], 1);
    if (p < CAP) jbuf[d * CAP + p] = src[i];
  }
}

// ---------------------------------------------------------------------------
// Yc[n][f] (12B) = { (ssp(X@W1^T+b1)@W2^T+b2) triplet , Vin[n][f] triplet }
// one wave per block, 16 nodes per block.
__global__ __launch_bounds__(64) void mlp_kernel(
    const unsigned short* __restrict__ X,    // [n][128] bf16
    const unsigned short* __restrict__ W1,   // [128][128] bf16
    const float* __restrict__ B1,            // [128]
    const unsigned short* __restrict__ W2,   // [384][128] bf16
    const float* __restrict__ B2,            // [384]
    const us4* __restrict__ Vin,             // [n][128] bf16 triplet
    unsigned short* __restrict__ Yc)         // [n][128] 12B records
{
  __shared__ float HT[128 * 17];
  const int lane = threadIdx.x;
  const int c    = lane & 15;
  const int quad = lane >> 4;
  const int m0   = blockIdx.x * 16;

  f32x4 acc[8];
#pragma unroll
  for (int t = 0; t < 8; t++) acc[t] = (f32x4){0.f, 0.f, 0.f, 0.f};
#pragma unroll
  for (int kk = 0; kk < 4; kk++) {
    short8 a = *(const short8*)(X + (size_t)(m0 + c) * 128 + kk * 32 + quad * 8);
#pragma unroll
    for (int t = 0; t < 8; t++) {
      short8 b = *(const short8*)(W1 + (size_t)(t * 16 + c) * 128 + kk * 32 + quad * 8);
      acc[t] = __builtin_amdgcn_mfma_f32_16x16x32_bf16(a, b, acc[t], 0, 0, 0);
    }
  }
#pragma unroll
  for (int t = 0; t < 8; t++) {
    float bias = B1[t * 16 + c];
    int k = t * 16 + c;
#pragma unroll
    for (int r = 0; r < 4; r++) {
      float h = acc[t][r] + bias;
      float sp = (h > 15.f) ? h : log1pf(__expf(h));
      sp -= 0.69314718056f;
      HT[k * 17 + quad * 4 + r] = sp;
    }
  }
  __syncthreads();

  // all 24 output tiles resident so a full 12B record can be written at once
  f32x4 acc2[3][8];
#pragma unroll
  for (int g = 0; g < 3; g++)
#pragma unroll
    for (int t = 0; t < 8; t++) acc2[g][t] = (f32x4){0.f, 0.f, 0.f, 0.f};
#pragma unroll
  for (int kk = 0; kk < 4; kk++) {
    short8 afr;
#pragma unroll
    for (int j = 0; j < 8; j++) {
      float hv = HT[(kk * 32 + quad * 8 + j) * 17 + c];
      afr[j] = (short)f2bf(hv);
    }
#pragma unroll
    for (int g = 0; g < 3; g++)
#pragma unroll
      for (int t = 0; t < 8; t++) {
        short8 b = *(const short8*)(W2 + (size_t)(g * 128 + t * 16 + c) * 128 + kk * 32 + quad * 8);
        acc2[g][t] = __builtin_amdgcn_mfma_f32_16x16x32_bf16(afr, b, acc2[g][t], 0, 0, 0);
      }
  }
#pragma unroll
  for (int t = 0; t < 8; t++) {
    int f = t * 16 + c;                      // feature in [0,128)
    float b0 = B2[f], b1 = B2[128 + f], b2 = B2[256 + f];
#pragma unroll
    for (int r = 0; r < 4; r++) {
      int m = quad * 4 + r;
      us4 vv = Vin[(size_t)(m0 + m) * 128 + f];
      unsigned p0 = f2bf(acc2[0][t][r] + b0);
      unsigned p1 = f2bf(acc2[1][t][r] + b1);
      unsigned p2 = f2bf(acc2[2][t][r] + b2);
      u3 rec;
      rec.a = p0 | (p1 << 16);
      rec.b = p2 | ((unsigned)vv.x << 16);
      rec.c = (unsigned)vv.y | ((unsigned)vv.z << 16);
      *(u3*)(Yc + ((size_t)(m0 + m) * 128 + f) * 6) = rec;
    }
  }
}

// ---------------------------------------------------------------------------
// pass 1 (fused W-GEMM): block = 1 dst node, 4 waves = (half) x (parity).
// 16-edge batches; phase B: UNCONDITIONAL clamped prefetch + mask accumulate.
__global__ __launch_bounds__(256, 4) void pass1_kernel(
    const float* __restrict__ x,       // [N,3]
    const unsigned short* __restrict__ combo1, // [N,128] 12B {phi012,v012}
    const float* __restrict__ v,       // [N,128,3] fp32 (epilogue add)
    const float* __restrict__ s,       // [N,128]
    const unsigned short* __restrict__ mvwB,  // [384][32] bf16 scale-folded
    const float* __restrict__ mv_b,           // [384]
    const int* __restrict__ jbuf,      // [N,CAP] src ids
    const int* __restrict__ deg,
    float* __restrict__ vnew, us4* __restrict__ vnew4,
    float* __restrict__ snew, unsigned short* __restrict__ snew_bf, int nNodes)
{
  __shared__ unsigned short Asn[BATCH * 32];  // 1 KB  A-tile (bf16 sn rows)
  __shared__ float4 Au[BATCH];                // 256 B {u0,u1,u2,invr}
  __shared__ us4 Wl[BATCH * 128];             // 16 KB per-batch weight triplets
  __shared__ float red[512];                  // 2 KB  cross-wave reduction

  const int tid  = threadIdx.x;
  const int wave = tid >> 6, lane = tid & 63;
  const int half = wave >> 1, split = wave & 1;
  const int i = blockIdx.x;
  const int f = lane + 64 * half;             // feature in [0,128)
  const int c = lane & 15, quad = lane >> 4;

  int cnt = deg[i]; if (cnt > CAP) cnt = CAP;
  const int base = i * CAP;

  // B-frags + bias for this wave's 6 tiles: {2w,2w+1,2w+8,2w+9,2w+16,2w+17}
  short8 bfr[6]; float bias[6];
#pragma unroll
  for (int p = 0; p < 3; p++)
#pragma unroll
    for (int h = 0; h < 2; h++) {
      int t = 2 * wave + h + 8 * p;
      bfr[p * 2 + h]  = *(const short8*)(mvwB + (size_t)(t * 16 + c) * 32 + quad * 8);
      bias[p * 2 + h] = mv_b[t * 16 + c];
    }

  const float xi0 = x[i * 3], xi1 = x[i * 3 + 1], xi2 = x[i * 3 + 2];
  int jv = (lane < cnt) ? jbuf[base + lane] : 0;

  float accV0 = 0.f, accV1 = 0.f, accV2 = 0.f, accS = 0.f;

  for (int bs = 0; bs < cnt; bs += BATCH) {
    int bcnt = cnt - bs; if (bcnt > BATCH) bcnt = BATCH;
    __syncthreads();                           // previous batch fully consumed

    if (wave == 0) {
      // ALL 64 lanes execute the shfl (source lanes must be exec-active);
      // e = bs + (lane&15) <= 48+15 = 63, always a valid source lane.
      int t16 = lane & (BATCH - 1);
      int e = bs + t16;
      int j = __shfl(jv, e);
      if (lane < BATCH && e < cnt) {
        float d0 = x[j * 3]     - xi0;
        float d1 = x[j * 3 + 1] - xi1;
        float d2 = x[j * 3 + 2] - xi2;
        float r = sqrtf(d0 * d0 + d1 * d1 + d2 * d2 + 1e-5f);
        float invr = 1.0f / r;
        Au[lane] = make_float4(d0 * invr, d1 * invr, d2 * invr, invr);
        float theta = r * 0.6283185307179586f;
        float s1, c1;
        __sincosf(theta, &s1, &c1);
        float c2 = 2.f * c1;
        float pm2 = s1, pm1 = c2 * s1;
        Asn[lane * 32 + 0] = f2bf(pm2);
        Asn[lane * 32 + 1] = f2bf(pm1);
#pragma unroll
        for (int l = 2; l < L_DIM; l++) {
          float cur = c2 * pm1 - pm2;
          Asn[lane * 32 + l] = f2bf(cur);
          pm2 = pm1; pm1 = cur;
        }
#pragma unroll
        for (int l = L_DIM; l < 32; l++) Asn[lane * 32 + l] = 0;
      }
    }
    __syncthreads();

    // single 16-row MFMA group
    {
      short8 a = *(const short8*)&Asn[c * 32 + quad * 8];
      f32x4 acc[6];
#pragma unroll
      for (int q = 0; q < 6; q++)
        acc[q] = __builtin_amdgcn_mfma_f32_16x16x32_bf16(
            a, bfr[q], (f32x4){0.f, 0.f, 0.f, 0.f}, 0, 0, 0);
#pragma unroll
      for (int r = 0; r < 4; r++) {
        int el = quad * 4 + r;
        if (el < bcnt) {
          float invr = Au[el].w;
#pragma unroll
          for (int h = 0; h < 2; h++) {
            float wp0 = fmaf(acc[h][r],     invr, bias[h]);
            float wp1 = fmaf(acc[2 + h][r], invr, bias[2 + h]);
            float wp2 = fmaf(acc[4 + h][r], invr, bias[4 + h]);
            float w0 = (wp0 < 5.f) ? 0.5f * (__cosf(wp0 * 0.6283185307179586f) + 1.f) : 0.f;
            float w1 = (wp1 < 5.f) ? 0.5f * (__cosf(wp1 * 0.6283185307179586f) + 1.f) : 0.f;
            float w2 = (wp2 < 5.f) ? 0.5f * (__cosf(wp2 * 0.6283185307179586f) + 1.f) : 0.f;
            us4 o; o.x = f2bf(w0); o.y = f2bf(w1); o.z = f2bf(w2); o.w = 0;
            Wl[el * 128 + wave * 32 + h * 16 + c] = o;
          }
        }
      }
    }
    __syncthreads();

    // phase B: unconditional clamped prefetch (array stays in registers),
    // validity applied as a float mask in the accumulate.
    u3 cb[8];
    float msk[8];
#pragma unroll
    for (int k = 0; k < 8; k++) {
      int e = split + 2 * k;
      int ec = (e < bcnt) ? e : 0;             // bcnt >= 1 inside the loop
      msk[k] = (e < bcnt) ? 1.f : 0.f;
      int j = __shfl(jv, bs + ec);
      cb[k] = *(const u3*)(combo1 + ((size_t)j * 128 + f) * 6);
    }
#pragma unroll
    for (int k = 0; k < 8; k++) {
      int e = split + 2 * k;
      int ec = (e < bcnt) ? e : 0;
      float4 u = Au[ec];
      us4 wv = Wl[ec * 128 + f];
      float ph0 = bf2f((unsigned short)(cb[k].a & 0xffff));
      float ph1 = bf2f((unsigned short)(cb[k].a >> 16));
      float ph2 = bf2f((unsigned short)(cb[k].b & 0xffff));
      float vx  = bf2f((unsigned short)(cb[k].b >> 16));
      float vy  = bf2f((unsigned short)(cb[k].c & 0xffff));
      float vz  = bf2f((unsigned short)(cb[k].c >> 16));
      float m0 = ph0 * bf2f(wv.x) * msk[k];
      float m1 = ph1 * bf2f(wv.y) * msk[k];
      float m2 = ph2 * bf2f(wv.z) * msk[k];
      accV0 = fmaf(vx, m0, fmaf(m2, u.x, accV0));
      accV1 = fmaf(vy, m0, fmaf(m2, u.y, accV1));
      accV2 = fmaf(vz, m0, fmaf(m2, u.z, accV2));
      accS += m1;
    }
  }

  const int idx = half * 64 + lane;
  __syncthreads();
  if (split == 1) {
    red[idx * 4 + 0] = accV0; red[idx * 4 + 1] = accV1;
    red[idx * 4 + 2] = accV2; red[idx * 4 + 3] = accS;
  }
  __syncthreads();
  if (split == 0) {
    accV0 += red[idx * 4 + 0]; accV1 += red[idx * 4 + 1];
    accV2 += red[idx * 4 + 2]; accS  += red[idx * 4 + 3];
    size_t b3 = (size_t)i * 384 + f * 3;
    float n0 = v[b3] + accV0, n1 = v[b3 + 1] + accV1, n2 = v[b3 + 2] + accV2;
    vnew[b3] = n0; vnew[b3 + 1] = n1; vnew[b3 + 2] = n2;
    us4 o; o.x = f2bf(n0); o.y = f2bf(n1); o.z = f2bf(n2); o.w = 0;
    vnew4[(size_t)i * 128 + f] = o;
    size_t b1 = (size_t)i * 128 + f;
    float sv = s[b1] + accS;
    snew[b1] = sv;
    snew_bf[b1] = f2bf(sv);
  }
}

// ---------------------------------------------------------------------------
// pass 2: block = 1 dst node, 4 waves = (feature half) x (edge parity).
// Unconditional clamped prefetch + mask accumulate; bound relaxed to (256,4).
__global__ __launch_bounds__(256, 4) void pass2_kernel(
    const float* __restrict__ vnew,   // [N,128,3] fp32
    const float* __restrict__ snew,   // [N,128]
    const unsigned short* __restrict__ combo2, // [N,128] 12B {s2 012, vnew 012}
    const int* __restrict__ jbuf, const int* __restrict__ deg,
    float* __restrict__ vout, float* __restrict__ sout, int nNodes)
{
  __shared__ float red[1024];
  const int wave = threadIdx.x >> 6, lane = threadIdx.x & 63;
  const int half = wave >> 1, split = wave & 1;
  const int i = blockIdx.x;
  const int f = lane + 64 * half;

  int cnt = deg[i]; if (cnt > CAP) cnt = CAP;
  const int base = i * CAP;
  int jv = (lane < cnt) ? jbuf[base + lane] : 0;

  float accU0 = 0.f, accU1 = 0.f, accU2 = 0.f;
  float accM0 = 0.f, accM1 = 0.f, accM2 = 0.f;

  for (int b0 = split; b0 < cnt; b0 += 16) {
    u3 cb[8];
    float msk[8];
#pragma unroll
    for (int k = 0; k < 8; k++) {
      int e = b0 + 2 * k;
      int ec = (e < cnt) ? e : 0;              // cnt >= 1 when loop entered
      msk[k] = (e < cnt) ? 1.f : 0.f;
      int j = __shfl(jv, ec);
      cb[k] = *(const u3*)(combo2 + ((size_t)j * 128 + f) * 6);
    }
#pragma unroll
    for (int k = 0; k < 8; k++) {
      accM0 = fmaf(bf2f((unsigned short)(cb[k].a & 0xffff)), msk[k], accM0);
      accM1 = fmaf(bf2f((unsigned short)(cb[k].a >> 16)),    msk[k], accM1);
      accM2 = fmaf(bf2f((unsigned short)(cb[k].b & 0xffff)), msk[k], accM2);
      accU0 = fmaf(bf2f((unsigned short)(cb[k].b >> 16)),    msk[k], accU0);
      accU1 = fmaf(bf2f((unsigned short)(cb[k].c & 0xffff)), msk[k], accU1);
      accU2 = fmaf(bf2f((unsigned short)(cb[k].c >> 16)),    msk[k], accU2);
    }
  }

  const int idx = half * 64 + lane;
  if (split == 1) {
    red[idx * 8 + 0] = accU0; red[idx * 8 + 1] = accU1; red[idx * 8 + 2] = accU2;
    red[idx * 8 + 3] = accM0; red[idx * 8 + 4] = accM1; red[idx * 8 + 5] = accM2;
  }
  __syncthreads();
  if (split == 0) {
    accU0 += red[idx * 8 + 0]; accU1 += red[idx * 8 + 1]; accU2 += red[idx * 8 + 2];
    accM0 += red[idx * 8 + 3]; accM1 += red[idx * 8 + 4]; accM2 += red[idx * 8 + 5];

    float dinv = 1.0f / (float)(cnt > 0 ? cnt : 1);
    float uv0 = accU0 * dinv, uv1 = accU1 * dinv, uv2 = accU2 * dinv;
    float avv = accM0 * dinv, asv = accM1 * dinv, ass = accM2 * dinv;
    float q = uv0 * uv0 + uv1 * uv1 + uv2 * uv2;
    float ds2 = (q / (q + 1e-5f)) * asv + ass;
    size_t b3 = (size_t)i * 384 + f * 3;
    vout[b3]     = vnew[b3]     + uv0 * avv;
    vout[b3 + 1] = vnew[b3 + 1] + uv1 * avv;
    vout[b3 + 2] = vnew[b3 + 2] + uv2 * avv;
    size_t b1 = (size_t)i * 128 + f;
    sout[b1] = snew[b1] + ds2;
  }
}

// ---------------------------------------------------------------------------
extern "C" void kernel_launch(void* const* d_in, const int* in_sizes, int n_in,
                              void* d_out, int out_size, void* d_ws, size_t ws_size,
                              hipStream_t stream)
{
  const float* x     = (const float*)d_in[0];
  const float* v     = (const float*)d_in[1];
  const float* s     = (const float*)d_in[2];
  const float* ms1_w = (const float*)d_in[3];
  const float* ms1_b = (const float*)d_in[4];
  const float* ms2_w = (const float*)d_in[5];
  const float* ms2_b = (const float*)d_in[6];
  const float* mv_w  = (const float*)d_in[7];
  const float* mv_b  = (const float*)d_in[8];
  const float* us1_w = (const float*)d_in[9];
  const float* us1_b = (const float*)d_in[10];
  const float* us2_w = (const float*)d_in[11];
  const float* us2_b = (const float*)d_in[12];
  const int*   src   = (const int*)d_in[13];
  const int*   dst   = (const int*)d_in[14];

  const int N = in_sizes[0] / 3;        // 10000
  const int E = in_sizes[13];           // 100000

  char* p = (char*)d_ws;
  auto alloc = [&](size_t bytes) -> void* {
    void* r = (void*)p;
    p += (bytes + 255) & ~(size_t)255;
    return r;
  };
  unsigned short* sbf   = (unsigned short*)alloc((size_t)N * 128 * 2);
  unsigned short* snbf  = (unsigned short*)alloc((size_t)N * 128 * 2);
  unsigned short* w_ms1 = (unsigned short*)alloc(16384 * 2);
  unsigned short* w_ms2 = (unsigned short*)alloc(49152 * 2);
  unsigned short* w_us1 = (unsigned short*)alloc(16384 * 2);
  unsigned short* w_us2 = (unsigned short*)alloc(49152 * 2);
  unsigned short* mvwB  = (unsigned short*)alloc(384 * 32 * 2);
  us4*   v4     = (us4*)alloc((size_t)N * 128 * 8);
  us4*   vnew4  = (us4*)alloc((size_t)N * 128 * 8);
  unsigned short* combo1 = (unsigned short*)alloc((size_t)N * 128 * 12);
  unsigned short* combo2 = (unsigned short*)alloc((size_t)N * 128 * 12);
  float* vnew   = (float*)alloc((size_t)N * 384 * 4);
  float* snew   = (float*)alloc((size_t)N * 128 * 4);
  int* cursor   = (int*)alloc((size_t)N * 4);           // becomes deg after fill
  int* jbuf     = (int*)alloc((size_t)N * CAP * 4);

  hipMemsetAsync(cursor, 0, (size_t)N * 4, stream);

  cast_fill_kernel<<<(N * 128 + 255) / 256, 256, 0, stream>>>(
      ms1_w, w_ms1, ms2_w, w_ms2, us1_w, w_us1, us2_w, w_us2,
      s, sbf, v, v4, mv_w, mvwB, src, dst, cursor, jbuf, N * 128, E);

  // combo1 = {phi triplet, v triplet}
  mlp_kernel<<<N / 16, 64, 0, stream>>>(sbf, w_ms1, ms1_b, w_ms2, ms2_b,
                                        v4, combo1);

  pass1_kernel<<<N, 256, 0, stream>>>(x, combo1, v, s, mvwB, mv_b,
                                      jbuf, cursor, vnew, vnew4, snew, snbf, N);

  // combo2 = {s2 triplet, vnew triplet}
  mlp_kernel<<<N / 16, 64, 0, stream>>>(snbf, w_us1, us1_b, w_us2, us2_b,
                                        vnew4, combo2);

  float* vout = (float*)d_out;
  float* sout = vout + (size_t)N * 384;
  pass2_kernel<<<N, 256, 0, stream>>>(vnew, snew, combo2, jbuf, cursor,
                                      vout, sout, N);
}